// Round 1
// baseline (811.572 us; speedup 1.0000x reference)
//
#include <hip/hip_runtime.h>
#include <hip/hip_bf16.h>

typedef __attribute__((ext_vector_type(4))) float f32x4;
typedef __attribute__((ext_vector_type(8))) short short8;

// ---------- helpers ----------
static __device__ __forceinline__ unsigned short f2b(float f) {
    // RNE float->bf16 (finite values)
    unsigned int x = __float_as_uint(f);
    unsigned int r = (x + 0x7fffu + ((x >> 16) & 1u)) >> 16;
    return (unsigned short)r;
}
static __device__ __forceinline__ float sigm(float x) { return 1.0f / (1.0f + __expf(-x)); }
static __device__ __forceinline__ float tanh_fast(float x) { return 2.0f / (1.0f + __expf(-2.0f * x)) - 1.0f; }

// ---------- convert inputs to bf16 workspace ----------
// fb  : features bf16 [N,512]
// wcat: [3072,1024] bf16 = rows 0..2559: [W_iofux | W_iofuh]; rows 2560..3071: [W_px | 0]
__global__ void convert_kernel(const float* __restrict__ feats, const float* __restrict__ Wx,
                               const float* __restrict__ Wh, const float* __restrict__ Wp,
                               unsigned short* __restrict__ fb, unsigned short* __restrict__ wcat,
                               int nf4, int nw4) {
    int idx = blockIdx.x * blockDim.x + threadIdx.x;
    int stride = gridDim.x * blockDim.x;
    int tot = nf4 + nw4;
    for (int i = idx; i < tot; i += stride) {
        float4 v;
        unsigned short* dst;
        if (i < nf4) {
            v = ((const float4*)feats)[i];
            dst = fb + (size_t)i * 4;
        } else {
            int t = i - nf4;
            int row = t >> 8;            // 256 quads per 1024-wide row
            int c4 = (t & 255) * 4;
            const float* src = nullptr;
            if (row < 2560) {
                src = (c4 < 512) ? (Wx + (size_t)row * 512 + c4)
                                 : (Wh + (size_t)row * 512 + (c4 - 512));
            } else {
                if (c4 < 512) src = Wp + (size_t)(row - 2560) * 512 + c4;
            }
            if (src) v = *(const float4*)src;
            else     v = make_float4(0.f, 0.f, 0.f, 0.f);
            dst = wcat + (size_t)row * 1024 + c4;
        }
        ushort4 o;
        o.x = f2b(v.x); o.y = f2b(v.y); o.z = f2b(v.z); o.w = f2b(v.w);
        *(ushort4*)dst = o;
    }
}

// ---------- fused level kernel ----------
// Computes, for nodes [s,e):  iofu = [x|ph] @ Wcat^T  (6 strips of 64 cols each tile),
// then gates + highway in epilogue. A-tile: rows=nodes(64), K=1024 (feat 512 | parent-h 512).
// Block: 256 thr (4 waves, 2x2 quadrants of 32x32). Tile 64x64 per strip.
__global__ __launch_bounds__(256, 2)
void level_kernel(const unsigned short* __restrict__ fb,    // [N,512] bf16
                  const unsigned short* __restrict__ wcat,  // [3072,1024] bf16
                  unsigned short* __restrict__ hb,          // [N,512] bf16 (parents in, this level out)
                  const float* __restrict__ bx, const float* __restrict__ bh,
                  const float* __restrict__ bp,
                  float* __restrict__ c_all,                // [N,512] f32
                  float* __restrict__ out,                  // [N,512] f32 (h_final)
                  int s, int e, int level) {
    __shared__ unsigned char smA[64 * 128];    // 64 rows x 64 bf16 (swizzled)
    __shared__ unsigned char smB[384 * 128];   // 6 strips x 64 rows x 64 bf16 (swizzled)

    const int tid = threadIdx.x;
    const int lane = tid & 63;
    const int w = tid >> 6;
    const int wr = w >> 1, wc = w & 1;
    const int nbase = s + blockIdx.x * 64;
    const int j0 = blockIdx.y * 64;

    f32x4 acc[6][2][2];
#pragma unroll
    for (int g = 0; g < 6; ++g)
#pragma unroll
        for (int mi = 0; mi < 2; ++mi)
#pragma unroll
            for (int ni = 0; ni < 2; ++ni)
                acc[g][mi][ni] = f32x4{0.f, 0.f, 0.f, 0.f};

    for (int ks = 0; ks < 16; ++ks) {
        __syncthreads();
        // ---- stage A (2 x 16B per thread): rows of [feat | parent-h]
#pragma unroll
        for (int i = 0; i < 2; ++i) {
            int sg = tid + i * 256;
            int r = sg >> 3, cs = sg & 7;
            int n = nbase + r;
            short8 v = {0, 0, 0, 0, 0, 0, 0, 0};
            if (n < e) {
                if (ks < 8) {
                    v = *(const short8*)(fb + (size_t)n * 512 + ks * 64 + cs * 8);
                } else if (level > 0) {
                    v = *(const short8*)(hb + (size_t)((n - 1) >> 3) * 512 + (ks - 8) * 64 + cs * 8);
                }
            }
            *(short8*)(smA + ((r * 128 + cs * 16) ^ ((r & 7) << 4))) = v;
        }
        // ---- stage B (12 x 16B per thread): 6 strips x 64 rows of Wcat
#pragma unroll
        for (int i = 0; i < 12; ++i) {
            int sg = tid + i * 256;
            int r = sg >> 3, cs = sg & 7;
            int g = r >> 6, rr = r & 63;
            int wrow = g * 512 + j0 + rr;
            short8 v = *(const short8*)(wcat + (size_t)wrow * 1024 + ks * 64 + cs * 8);
            *(short8*)(smB + ((r * 128 + cs * 16) ^ ((r & 7) << 4))) = v;
        }
        __syncthreads();

#pragma unroll
        for (int kk = 0; kk < 2; ++kk) {
            const int kb = kk * 64 + ((lane >> 4) << 4);   // byte offset in row
            short8 a[2];
#pragma unroll
            for (int mi = 0; mi < 2; ++mi) {
                int ar = wr * 32 + mi * 16 + (lane & 15);
                a[mi] = *(const short8*)(smA + ((ar * 128 + kb) ^ ((ar & 7) << 4)));
            }
#pragma unroll
            for (int g = 0; g < 6; ++g) {
                if (g == 5 && ks >= 8) continue;   // px strip: only K<512 (B is zero above)
                int br0 = g * 64 + wc * 32 + (lane & 15);
                int br1 = br0 + 16;
                short8 b0 = *(const short8*)(smB + ((br0 * 128 + kb) ^ ((br0 & 7) << 4)));
                short8 b1 = *(const short8*)(smB + ((br1 * 128 + kb) ^ ((br1 & 7) << 4)));
                acc[g][0][0] = __builtin_amdgcn_mfma_f32_16x16x32_bf16(a[0], b0, acc[g][0][0], 0, 0, 0);
                acc[g][0][1] = __builtin_amdgcn_mfma_f32_16x16x32_bf16(a[0], b1, acc[g][0][1], 0, 0, 0);
                acc[g][1][0] = __builtin_amdgcn_mfma_f32_16x16x32_bf16(a[1], b0, acc[g][1][0], 0, 0, 0);
                acc[g][1][1] = __builtin_amdgcn_mfma_f32_16x16x32_bf16(a[1], b1, acc[g][1][1], 0, 0, 0);
            }
        }
    }

    // ---- epilogue: gates + highway; C/D layout col=lane&15, row=(lane>>4)*4+q
    const int colb = j0 + wc * 32 + (lane & 15);
#pragma unroll
    for (int ni = 0; ni < 2; ++ni) {
        const int j = colb + ni * 16;
        const float Bi = bx[j]        + bh[j];
        const float Bo = bx[j + 512]  + bh[j + 512];
        const float Bf = bx[j + 1024] + bh[j + 1024];
        const float Bu = bx[j + 1536] + bh[j + 1536];
        const float Br = bx[j + 2048] + bh[j + 2048];
        const float Bp = bp[j];
#pragma unroll
        for (int mi = 0; mi < 2; ++mi) {
            const int rowb = wr * 32 + mi * 16 + ((lane >> 4) << 2);
#pragma unroll
            for (int q = 0; q < 4; ++q) {
                int n = nbase + rowb + q;
                if (n >= e) continue;
                float gi = sigm(acc[0][mi][ni][q] + Bi);
                float go = sigm(acc[1][mi][ni][q] + Bo);
                float gf = sigm(acc[2][mi][ni][q] + Bf);
                float gu = tanh_fast(acc[3][mi][ni][q] + Bu);
                float gr = sigm(acc[4][mi][ni][q] + Br);
                float pp = acc[5][mi][ni][q] + Bp;
                float pc = (level > 0) ? c_all[(size_t)((n - 1) >> 3) * 512 + j] : 0.0f;
                float cg = gi * gu + gf * pc;
                float hh = go * tanh_fast(cg);
                float hf = gr * hh + (1.0f - gr) * pp;
                size_t o = (size_t)n * 512 + j;
                c_all[o] = cg;
                out[o] = hf;
                hb[o] = f2b(hf);
            }
        }
    }
}

// ---------- host ----------
extern "C" void kernel_launch(void* const* d_in, const int* in_sizes, int n_in,
                              void* d_out, int out_size, void* d_ws, size_t ws_size,
                              hipStream_t stream) {
    const float* feats = (const float*)d_in[0];
    const float* Wx = (const float*)d_in[1];
    const float* bx = (const float*)d_in[2];
    const float* Wh = (const float*)d_in[3];
    const float* bh = (const float*)d_in[4];
    const float* Wp = (const float*)d_in[5];
    const float* bp = (const float*)d_in[6];
    float* out = (float*)d_out;

    const int N = in_sizes[0] / 512;

    // workspace layout
    unsigned short* fb = (unsigned short*)d_ws;                 // N*512 bf16
    unsigned short* wcat = fb + (size_t)N * 512;                // 3072*1024 bf16
    unsigned short* hb = wcat + (size_t)3072 * 1024;            // N*512 bf16
    float* c_all = (float*)(hb + (size_t)N * 512);              // N*512 f32

    const int nf4 = N * 512 / 4;
    const int nw4 = 3072 * 1024 / 4;
    convert_kernel<<<dim3(2048), dim3(256), 0, stream>>>(feats, Wx, Wh, Wp, fb, wcat, nf4, nw4);

    // BFS level bounds of the complete 8-ary tree
    int bounds[16];
    bounds[0] = 0;
    long cnt = 1;
    int nl = 0;
    while (bounds[nl] < N) {
        long nxt = (long)bounds[nl] + cnt;
        if (nxt > N) nxt = N;
        bounds[nl + 1] = (int)nxt;
        nl++;
        cnt *= 8;
    }

    for (int l = 0; l < nl; ++l) {
        int s = bounds[l], e = bounds[l + 1];
        int rows = e - s;
        dim3 grid((rows + 63) / 64, 8);
        level_kernel<<<grid, dim3(256), 0, stream>>>(fb, wcat, hb, bx, bh, bp, c_all, out, s, e, l);
    }
}

// Round 2
// 681.817 us; speedup vs baseline: 1.1903x; 1.1903x over previous
//
#include <hip/hip_runtime.h>
#include <hip/hip_bf16.h>

typedef __attribute__((ext_vector_type(4))) float f32x4;
typedef __attribute__((ext_vector_type(8))) short short8;

// ---------- helpers ----------
static __device__ __forceinline__ unsigned short f2b(float f) {
    unsigned int x = __float_as_uint(f);
    return (unsigned short)((x + 0x7fffu + ((x >> 16) & 1u)) >> 16);
}
static __device__ __forceinline__ float sigm(float x) { return 1.0f / (1.0f + __expf(-x)); }
static __device__ __forceinline__ float tanh_fast(float x) { return 2.0f / (1.0f + __expf(-2.0f * x)) - 1.0f; }

static __device__ __forceinline__ void gload16(const void* g, void* l) {
    __builtin_amdgcn_global_load_lds((const __attribute__((address_space(1))) void*)g,
                                     (__attribute__((address_space(3))) void*)l, 16, 0, 0);
}

// ---------- convert inputs to bf16 workspace ----------
__global__ void convert_kernel(const float* __restrict__ feats, const float* __restrict__ Wx,
                               const float* __restrict__ Wh, const float* __restrict__ Wp,
                               unsigned short* __restrict__ fb, unsigned short* __restrict__ wcat,
                               int nf4, int nw4) {
    int idx = blockIdx.x * blockDim.x + threadIdx.x;
    int stride = gridDim.x * blockDim.x;
    int tot = nf4 + nw4;
    for (int i = idx; i < tot; i += stride) {
        float4 v;
        unsigned short* dst;
        if (i < nf4) {
            v = ((const float4*)feats)[i];
            dst = fb + (size_t)i * 4;
        } else {
            int t = i - nf4;
            int row = t >> 8;
            int c4 = (t & 255) * 4;
            const float* src = nullptr;
            if (row < 2560) {
                src = (c4 < 512) ? (Wx + (size_t)row * 512 + c4)
                                 : (Wh + (size_t)row * 512 + (c4 - 512));
            } else {
                if (c4 < 512) src = Wp + (size_t)(row - 2560) * 512 + c4;
            }
            if (src) v = *(const float4*)src;
            else     v = make_float4(0.f, 0.f, 0.f, 0.f);
            dst = wcat + (size_t)row * 1024 + c4;
        }
        ushort4 o;
        o.x = f2b(v.x); o.y = f2b(v.y); o.z = f2b(v.z); o.w = f2b(v.w);
        *(ushort4*)dst = o;
    }
}

// ---------- fused level kernel ----------
// Tile: 128 rows x (6 strips x 64 cols). K-step 32, double-buffered LDS (2x32KB),
// global_load_lds staging with pre-swizzled source, 2-phase pipeline.
// 4 waves: wr=w>>1 picks 64-row half (M_rep=4 x 16), wc=w&1 picks 32-col half (ni 2 x 16).
__global__ __launch_bounds__(256, 2)
void level_kernel(const unsigned short* __restrict__ fb,    // [N,512] bf16
                  const unsigned short* __restrict__ wcat,  // [3072,1024] bf16
                  unsigned short* __restrict__ hb,          // [N,512] bf16
                  const float* __restrict__ bx, const float* __restrict__ bh,
                  const float* __restrict__ bp,
                  float* __restrict__ c_all,                // [N,512] f32
                  float* __restrict__ out,                  // [N,512] f32
                  int s, int e, int level, int nks) {
    __shared__ unsigned char sm[65536];

    const int tid = threadIdx.x;
    const int lane = tid & 63;
    const int w = tid >> 6;
    const int wr = w >> 1, wc = w & 1;
    const int nbase = s + blockIdx.x * 128;
    const int j0 = blockIdx.y * 64;

    // ---- staging source offsets (bf16-element units). seg = i*256+tid:
    // i=0,1 -> A (128 rows x 4 slots of 8 elems); i=2..7 -> B (384 rows x 4 slots)
    unsigned int aOff[2], hOff[2], bOff[6];
#pragma unroll
    for (int i = 0; i < 2; ++i) {
        int seg = i * 256 + tid;
        int row = seg >> 2;                       // 0..127
        int slot = (seg & 3) ^ ((row >> 1) & 3);  // pre-swizzled global slot
        int n = nbase + row; if (n > e - 1) n = e - 1;
        aOff[i] = (unsigned)n * 512u + slot * 8;
        int pr = (n - 1) >> 3; if (pr < 0) pr = 0;
        hOff[i] = (unsigned)pr * 512u + slot * 8;
    }
#pragma unroll
    for (int i = 0; i < 6; ++i) {
        int r3 = i * 256 + tid;                   // seg-512: 0..1535
        int row = r3 >> 2;                        // 0..383
        int slot = (r3 & 3) ^ ((row >> 1) & 3);
        int wrow = (row >> 6) * 512 + j0 + (row & 63);
        bOff[i] = (unsigned)wrow * 1024u + slot * 8;
    }
    const unsigned ldsW = (unsigned)w * 1024u;    // wave-uniform segment base per call

    // ---- ds_read base offsets (swizzled; constant across ks) ----
    const int slotx = ((lane >> 4) ^ ((lane >> 1) & 3)) << 4;
    const int abase = (wr * 64 + (lane & 15)) * 64 + slotx;           // A row*64B
    const int bbase = 8192 + (wc * 32 + (lane & 15)) * 64 + slotx;    // B region

    f32x4 acc[6][4][2];
#pragma unroll
    for (int g = 0; g < 6; ++g)
#pragma unroll
        for (int mi = 0; mi < 4; ++mi)
#pragma unroll
            for (int ni = 0; ni < 2; ++ni)
                acc[g][mi][ni] = f32x4{0.f, 0.f, 0.f, 0.f};

    // ---- prologue: stage ks=0 into buffer 0 ----
#pragma unroll
    for (int i = 0; i < 2; ++i)
        gload16(fb + aOff[i], sm + i * 4096 + ldsW);
#pragma unroll
    for (int i = 0; i < 6; ++i)
        gload16(wcat + bOff[i], sm + (i + 2) * 4096 + ldsW);
    __syncthreads();

    for (int ks = 0; ks < nks; ++ks) {
        // ---- stage ks+1 into the other buffer (async, in flight during MFMA) ----
        if (ks + 1 < nks) {
            unsigned char* basep = sm + ((ks + 1) & 1) * 32768;
            const int ksn = ks + 1;
#pragma unroll
            for (int i = 0; i < 2; ++i) {
                const unsigned short* src = (ksn < 16)
                    ? fb + aOff[i] + ksn * 32
                    : hb + hOff[i] + (ksn - 16) * 32;
                gload16(src, basep + i * 4096 + ldsW);
            }
#pragma unroll
            for (int i = 0; i < 6; ++i)
                gload16(wcat + bOff[i] + ksn * 32, basep + (i + 2) * 4096 + ldsW);
        }
        // ---- compute current buffer ----
        const unsigned char* cur = sm + (ks & 1) * 32768;
        short8 a[4];
#pragma unroll
        for (int mi = 0; mi < 4; ++mi)
            a[mi] = *(const short8*)(cur + abase + mi * 1024);
#pragma unroll
        for (int g = 0; g < 6; ++g) {
            if (g == 5 && ks >= 16) break;   // px strip: B is zero for K>=512
            short8 b0 = *(const short8*)(cur + bbase + g * 4096);
            short8 b1 = *(const short8*)(cur + bbase + g * 4096 + 1024);
#pragma unroll
            for (int mi = 0; mi < 4; ++mi) {
                acc[g][mi][0] = __builtin_amdgcn_mfma_f32_16x16x32_bf16(a[mi], b0, acc[g][mi][0], 0, 0, 0);
                acc[g][mi][1] = __builtin_amdgcn_mfma_f32_16x16x32_bf16(a[mi], b1, acc[g][mi][1], 0, 0, 0);
            }
        }
        __syncthreads();   // drains vmcnt(0) for the stage + lgkm; one barrier per K-step
    }

    // ---- epilogue: gates + highway. C/D layout: col=lane&15, row=(lane>>4)*4+q
    const int colb = j0 + wc * 32 + (lane & 15);
#pragma unroll
    for (int ni = 0; ni < 2; ++ni) {
        const int j = colb + ni * 16;
        const float Bi = bx[j]        + bh[j];
        const float Bo = bx[j + 512]  + bh[j + 512];
        const float Bf = bx[j + 1024] + bh[j + 1024];
        const float Bu = bx[j + 1536] + bh[j + 1536];
        const float Br = bx[j + 2048] + bh[j + 2048];
        const float Bp = bp[j];
#pragma unroll
        for (int mi = 0; mi < 4; ++mi) {
            const int rowb = wr * 64 + mi * 16 + ((lane >> 4) << 2);
#pragma unroll
            for (int q = 0; q < 4; ++q) {
                int n = nbase + rowb + q;
                if (n >= e) continue;
                float gi = sigm(acc[0][mi][ni][q] + Bi);
                float go = sigm(acc[1][mi][ni][q] + Bo);
                float gf = sigm(acc[2][mi][ni][q] + Bf);
                float gu = tanh_fast(acc[3][mi][ni][q] + Bu);
                float gr = sigm(acc[4][mi][ni][q] + Br);
                float pp = acc[5][mi][ni][q] + Bp;
                float pc = (level > 0) ? c_all[(size_t)((n - 1) >> 3) * 512 + j] : 0.0f;
                float cg = gi * gu + gf * pc;
                float hh = go * tanh_fast(cg);
                float hf = gr * hh + (1.0f - gr) * pp;
                size_t o = (size_t)n * 512 + j;
                c_all[o] = cg;
                out[o] = hf;
                hb[o] = f2b(hf);
            }
        }
    }
}

// ---------- host ----------
extern "C" void kernel_launch(void* const* d_in, const int* in_sizes, int n_in,
                              void* d_out, int out_size, void* d_ws, size_t ws_size,
                              hipStream_t stream) {
    const float* feats = (const float*)d_in[0];
    const float* Wx = (const float*)d_in[1];
    const float* bx = (const float*)d_in[2];
    const float* Wh = (const float*)d_in[3];
    const float* bh = (const float*)d_in[4];
    const float* Wp = (const float*)d_in[5];
    const float* bp = (const float*)d_in[6];
    float* out = (float*)d_out;

    const int N = in_sizes[0] / 512;

    unsigned short* fb = (unsigned short*)d_ws;                 // N*512 bf16
    unsigned short* wcat = fb + (size_t)N * 512;                // 3072*1024 bf16
    unsigned short* hb = wcat + (size_t)3072 * 1024;            // N*512 bf16
    float* c_all = (float*)(hb + (size_t)N * 512);              // N*512 f32

    const int nf4 = N * 512 / 4;
    const int nw4 = 3072 * 1024 / 4;
    convert_kernel<<<dim3(2048), dim3(256), 0, stream>>>(feats, Wx, Wh, Wp, fb, wcat, nf4, nw4);

    int bounds[16];
    bounds[0] = 0;
    long cnt = 1;
    int nl = 0;
    while (bounds[nl] < N) {
        long nxt = (long)bounds[nl] + cnt;
        if (nxt > N) nxt = N;
        bounds[nl + 1] = (int)nxt;
        nl++;
        cnt *= 8;
    }

    for (int l = 0; l < nl; ++l) {
        int s = bounds[l], e = bounds[l + 1];
        int rows = e - s;
        int nks = (l > 0) ? 32 : 16;
        dim3 grid((rows + 127) / 128, 8);
        level_kernel<<<grid, dim3(256), 0, stream>>>(fb, wcat, hb, bx, bh, bp, c_all, out, s, e, l, nks);
    }
}